// Round 1
// baseline (1605.918 us; speedup 1.0000x reference)
//
#include <hip/hip_runtime.h>

#define NEG_SLOPE 0.2f

// ---------------------------------------------------------------------------
// Fused GEMM + attention-logit kernel.
//   H[n, BN]   = X[n, 128] @ W[128, BN]
//   As[n, hd]  = sum_c H[n, hd*C+c] * atts[hd*C+c]
//   Ad[n, hd]  = sum_c H[n, hd*C+c] * attd[hd*C+c]
// BN: output cols; BM: rows per block tile; C: channels per head.
// Block = 256 threads, each computing a 4x4 register tile.
// ---------------------------------------------------------------------------
template<int BN, int BM, int C>
__global__ __launch_bounds__(256) void gemm_att(
    const float* __restrict__ X, const float* __restrict__ W,
    const float* __restrict__ atts, const float* __restrict__ attd,
    float* __restrict__ H, float* __restrict__ As, float* __restrict__ Ad,
    int n)
{
    constexpr int K  = 128;
    constexpr int CG = BN / 4;          // column groups of 4
    constexpr int RW = C / 4;           // shuffle-reduce width (lanes per head)
    constexpr int HEADS = BN / C;

    __shared__ float Wl[K * BN];        // W staged whole (64KB / 32KB)
    __shared__ float Xl[K * BM];        // X tile, k-major (transposed)

    const int t = threadIdx.x;
    for (int i = t; i < K * BN / 4; i += 256)
        ((float4*)Wl)[i] = ((const float4*)W)[i];

    const int cg   = t % CG;
    const int rg   = t / CG;
    const int col0 = cg * 4;
    const int head = col0 / C;
    const float s0 = atts[col0], s1 = atts[col0+1], s2 = atts[col0+2], s3 = atts[col0+3];
    const float d0 = attd[col0], d1 = attd[col0+1], d2 = attd[col0+2], d3 = attd[col0+3];

    const int numTiles = (n + BM - 1) / BM;
    for (int tile = blockIdx.x; tile < numTiles; tile += gridDim.x) {
        const int row0 = tile * BM;
        __syncthreads();   // covers Wl load on first iter, Xl reuse after
        // Stage X tile transposed: Xl[k*BM + r]
        for (int i = t; i < BM * (K / 4); i += 256) {
            int r = i % BM, k4 = i / BM;
            int row = row0 + r;
            float4 v = make_float4(0.f, 0.f, 0.f, 0.f);
            if (row < n) v = ((const float4*)(X + (size_t)row * K))[k4];
            Xl[(k4*4+0)*BM + r] = v.x;
            Xl[(k4*4+1)*BM + r] = v.y;
            Xl[(k4*4+2)*BM + r] = v.z;
            Xl[(k4*4+3)*BM + r] = v.w;
        }
        __syncthreads();

        float acc[4][4];
        #pragma unroll
        for (int a = 0; a < 4; ++a)
            #pragma unroll
            for (int b = 0; b < 4; ++b) acc[a][b] = 0.f;

        #pragma unroll 8
        for (int k = 0; k < K; ++k) {
            float4 a = ((const float4*)(Xl + k * BM))[rg];
            float4 b = ((const float4*)(Wl + k * BN))[cg];
            acc[0][0] += a.x*b.x; acc[0][1] += a.x*b.y; acc[0][2] += a.x*b.z; acc[0][3] += a.x*b.w;
            acc[1][0] += a.y*b.x; acc[1][1] += a.y*b.y; acc[1][2] += a.y*b.z; acc[1][3] += a.y*b.w;
            acc[2][0] += a.z*b.x; acc[2][1] += a.z*b.y; acc[2][2] += a.z*b.z; acc[2][3] += a.z*b.w;
            acc[3][0] += a.w*b.x; acc[3][1] += a.w*b.y; acc[3][2] += a.w*b.z; acc[3][3] += a.w*b.w;
        }

        #pragma unroll
        for (int ri = 0; ri < 4; ++ri) {
            int row = row0 + rg * 4 + ri;
            bool ok = row < n;
            if (ok)
                ((float4*)(H + (size_t)row * BN))[cg] =
                    make_float4(acc[ri][0], acc[ri][1], acc[ri][2], acc[ri][3]);
            float ps = acc[ri][0]*s0 + acc[ri][1]*s1 + acc[ri][2]*s2 + acc[ri][3]*s3;
            float pd = acc[ri][0]*d0 + acc[ri][1]*d1 + acc[ri][2]*d2 + acc[ri][3]*d3;
            #pragma unroll
            for (int off = RW / 2; off > 0; off >>= 1) {
                ps += __shfl_down(ps, off, RW);
                pd += __shfl_down(pd, off, RW);
            }
            if (ok && (cg % RW) == 0) {
                As[(size_t)row * HEADS + head] = ps;
                Ad[(size_t)row * HEADS + head] = pd;
            }
        }
    }
}

// ---------------------------------------------------------------------------
// One-pass edge aggregation (softmax normalization deferred to node pass):
//   w = exp(leakyrelu(As[src] + Ad[dst]))
//   Out[dst, i] += w * H[src, i];  Den[dst, head] += w
// One thread per (edge, feature). F = feature width, power of 2.
// ---------------------------------------------------------------------------
template<int F, int HEADS>
__global__ __launch_bounds__(256) void edge_agg(
    const int* __restrict__ ei, int E, int Etot,
    const float* __restrict__ H, const float* __restrict__ As,
    const float* __restrict__ Ad,
    float* __restrict__ Out, float* __restrict__ Den)
{
    constexpr int C = F / HEADS;
    unsigned gid = blockIdx.x * 256u + threadIdx.x;
    unsigned e = gid / (unsigned)F;
    if (e >= (unsigned)Etot) return;
    int i = gid % F;
    int src, dst;
    if (e < (unsigned)E) { src = ei[e]; dst = ei[E + e]; }
    else                 { src = dst = (int)(e - (unsigned)E); }
    int head = i / C;
    float ev = As[(size_t)src * HEADS + head] + Ad[(size_t)dst * HEADS + head];
    ev = ev > 0.f ? ev : NEG_SLOPE * ev;
    float w = __expf(ev);
    atomicAdd(&Out[(size_t)dst * F + i], w * H[(size_t)src * F + i]);
    if (i % C == 0) atomicAdd(&Den[(size_t)dst * HEADS + head], w);
}

// ---------------------------------------------------------------------------
// Node finish: divide by softmax denom, add bias, optional ELU. In-place OK.
// ---------------------------------------------------------------------------
template<int F, int HEADS, bool DO_ELU>
__global__ __launch_bounds__(256) void node_finish(
    const float* __restrict__ Acc, const float* __restrict__ Den,
    const float* __restrict__ bias, float* __restrict__ Dst, int n)
{
    constexpr int C = F / HEADS;
    unsigned gid = blockIdx.x * 256u + threadIdx.x;
    if (gid >= (unsigned)n * (unsigned)F) return;
    unsigned node = gid / F;
    int i = gid % F;
    int head = i / C;
    float v = Acc[gid] / (Den[(size_t)node * HEADS + head] + 1e-16f) + bias[i];
    if (DO_ELU) v = v > 0.f ? v : (__expf(v) - 1.f);
    Dst[gid] = v;
}

extern "C" void kernel_launch(void* const* d_in, const int* in_sizes, int n_in,
                              void* d_out, int out_size, void* d_ws, size_t ws_size,
                              hipStream_t stream)
{
    (void)n_in; (void)out_size; (void)ws_size;
    const float* x   = (const float*)d_in[0];
    const int*   ei  = (const int*)  d_in[1];
    const float* W1  = (const float*)d_in[2];
    const float* as1 = (const float*)d_in[3];
    const float* ad1 = (const float*)d_in[4];
    const float* b1  = (const float*)d_in[5];
    const float* W2  = (const float*)d_in[6];
    const float* as2 = (const float*)d_in[7];
    const float* ad2 = (const float*)d_in[8];
    const float* b2  = (const float*)d_in[9];
    float* out = (float*)d_out;

    const int n    = in_sizes[0] / 128;   // 100000
    const int E    = in_sizes[1] / 2;     // 1600000
    const int Etot = E + n;               // + self loops

    // Workspace layout (floats). Layer-2 buffers overlay consumed layer-1 ones.
    float* ws  = (float*)d_ws;
    float* H1  = ws;                          // n*128   (layer2: H2 uses n*64 of it)
    float* As1 = H1  + (size_t)n * 128;       // n*4     (layer2: As2 = n)
    float* Ad1 = As1 + (size_t)n * 4;         // n*4     (layer2: Ad2 = n)
    float* Den = Ad1 + (size_t)n * 4;         // n*4     (layer2: n)
    float* Agg = Den + (size_t)n * 4;         // n*128   (becomes X2 in-place after ELU)

    // ---- Layer 1 ----
    // Zero Den + Agg (contiguous region)
    hipMemsetAsync(Den, 0, sizeof(float) * ((size_t)n * 4 + (size_t)n * 128), stream);

    gemm_att<128, 32, 32><<<(n + 31) / 32, 256, 0, stream>>>(x, W1, as1, ad1, H1, As1, Ad1, n);

    {
        unsigned total = (unsigned)Etot * 128u;
        edge_agg<128, 4><<<(total + 255) / 256, 256, 0, stream>>>(ei, E, Etot, H1, As1, Ad1, Agg, Den);
    }

    node_finish<128, 4, true><<<(((unsigned)n * 128u) + 255) / 256, 256, 0, stream>>>(
        Agg, Den, b1, Agg, n);   // in-place: Agg becomes X2 = elu(out1 + b1)

    // ---- Layer 2 ----
    hipMemsetAsync(Den, 0, sizeof(float) * (size_t)n, stream);
    hipMemsetAsync(out, 0, sizeof(float) * (size_t)n * 64, stream);

    gemm_att<64, 64, 64><<<(n + 63) / 64, 256, 0, stream>>>(Agg, W2, as2, ad2, H1, As1, Ad1, n);

    {
        unsigned total = (unsigned)Etot * 64u;
        edge_agg<64, 1><<<(total + 255) / 256, 256, 0, stream>>>(ei, E, Etot, H1, As1, Ad1, out, Den);
    }

    node_finish<64, 1, false><<<(((unsigned)n * 64u) + 255) / 256, 256, 0, stream>>>(
        out, Den, b2, out, n);
}

// Round 2
// 764.965 us; speedup vs baseline: 2.0993x; 2.0993x over previous
//
#include <hip/hip_runtime.h>

#define NEG_SLOPE 0.2f

// ---------------------------------------------------------------------------
// Fused GEMM + attention-logit kernel.
//   H[n, BN]   = X[n, 128] @ W[128, BN]
//   As[n, hd]  = sum_c H[n, hd*C+c] * atts[hd*C+c]
//   Ad[n, hd]  = sum_c H[n, hd*C+c] * attd[hd*C+c]
// ---------------------------------------------------------------------------
template<int BN, int BM, int C>
__global__ __launch_bounds__(256) void gemm_att(
    const float* __restrict__ X, const float* __restrict__ W,
    const float* __restrict__ atts, const float* __restrict__ attd,
    float* __restrict__ H, float* __restrict__ As, float* __restrict__ Ad,
    int n)
{
    constexpr int K  = 128;
    constexpr int CG = BN / 4;          // column groups of 4
    constexpr int RW = C / 4;           // shuffle-reduce width (lanes per head)
    constexpr int HEADS = BN / C;

    __shared__ float Wl[K * BN];
    __shared__ float Xl[K * BM];

    const int t = threadIdx.x;
    for (int i = t; i < K * BN / 4; i += 256)
        ((float4*)Wl)[i] = ((const float4*)W)[i];

    const int cg   = t % CG;
    const int rg   = t / CG;
    const int col0 = cg * 4;
    const int head = col0 / C;
    const float s0 = atts[col0], s1 = atts[col0+1], s2 = atts[col0+2], s3 = atts[col0+3];
    const float d0 = attd[col0], d1 = attd[col0+1], d2 = attd[col0+2], d3 = attd[col0+3];

    const int numTiles = (n + BM - 1) / BM;
    for (int tile = blockIdx.x; tile < numTiles; tile += gridDim.x) {
        const int row0 = tile * BM;
        __syncthreads();
        for (int i = t; i < BM * (K / 4); i += 256) {
            int r = i % BM, k4 = i / BM;
            int row = row0 + r;
            float4 v = make_float4(0.f, 0.f, 0.f, 0.f);
            if (row < n) v = ((const float4*)(X + (size_t)row * K))[k4];
            Xl[(k4*4+0)*BM + r] = v.x;
            Xl[(k4*4+1)*BM + r] = v.y;
            Xl[(k4*4+2)*BM + r] = v.z;
            Xl[(k4*4+3)*BM + r] = v.w;
        }
        __syncthreads();

        float acc[4][4];
        #pragma unroll
        for (int a = 0; a < 4; ++a)
            #pragma unroll
            for (int b = 0; b < 4; ++b) acc[a][b] = 0.f;

        #pragma unroll 8
        for (int k = 0; k < K; ++k) {
            float4 a = ((const float4*)(Xl + k * BM))[rg];
            float4 b = ((const float4*)(Wl + k * BN))[cg];
            acc[0][0] += a.x*b.x; acc[0][1] += a.x*b.y; acc[0][2] += a.x*b.z; acc[0][3] += a.x*b.w;
            acc[1][0] += a.y*b.x; acc[1][1] += a.y*b.y; acc[1][2] += a.y*b.z; acc[1][3] += a.y*b.w;
            acc[2][0] += a.z*b.x; acc[2][1] += a.z*b.y; acc[2][2] += a.z*b.z; acc[2][3] += a.z*b.w;
            acc[3][0] += a.w*b.x; acc[3][1] += a.w*b.y; acc[3][2] += a.w*b.z; acc[3][3] += a.w*b.w;
        }

        #pragma unroll
        for (int ri = 0; ri < 4; ++ri) {
            int row = row0 + rg * 4 + ri;
            bool ok = row < n;
            if (ok)
                ((float4*)(H + (size_t)row * BN))[cg] =
                    make_float4(acc[ri][0], acc[ri][1], acc[ri][2], acc[ri][3]);
            float ps = acc[ri][0]*s0 + acc[ri][1]*s1 + acc[ri][2]*s2 + acc[ri][3]*s3;
            float pd = acc[ri][0]*d0 + acc[ri][1]*d1 + acc[ri][2]*d2 + acc[ri][3]*d3;
            #pragma unroll
            for (int off = RW / 2; off > 0; off >>= 1) {
                ps += __shfl_down(ps, off, RW);
                pd += __shfl_down(pd, off, RW);
            }
            if (ok && (cg % RW) == 0) {
                As[(size_t)row * HEADS + head] = ps;
                Ad[(size_t)row * HEADS + head] = pd;
            }
        }
    }
}

// ---------------------------------------------------------------------------
// CSR build: histogram of dst, block-wise exclusive scan, scatter src ids.
// After scatter, offs[v] == end(v); beg(v) = (v==0 ? 0 : offs[v-1]).
// ---------------------------------------------------------------------------
__global__ __launch_bounds__(256) void hist_kernel(
    const int* __restrict__ ei, int E, int Etot, int* __restrict__ deg)
{
    int e = blockIdx.x * 256 + threadIdx.x;
    if (e >= Etot) return;
    int dst = (e < E) ? ei[E + e] : (e - E);
    atomicAdd(&deg[dst], 1);
}

// each block scans 1024 elements (in-place safe: reads own range before writes)
__global__ __launch_bounds__(256) void scan_blocks(
    int* __restrict__ data, int n, int* __restrict__ bsum)
{
    __shared__ int s[256];
    int t = threadIdx.x;
    int idx = blockIdx.x * 1024 + t * 4;
    int4 v = make_int4(0, 0, 0, 0);
    if (idx + 3 < n)      v = *(const int4*)(data + idx);
    else {
        if (idx     < n) v.x = data[idx];
        if (idx + 1 < n) v.y = data[idx+1];
        if (idx + 2 < n) v.z = data[idx+2];
        if (idx + 3 < n) v.w = data[idx+3];
    }
    int tsum = v.x + v.y + v.z + v.w;
    s[t] = tsum;
    __syncthreads();
    for (int off = 1; off < 256; off <<= 1) {
        int x = (t >= off) ? s[t - off] : 0;
        __syncthreads();
        s[t] += x;
        __syncthreads();
    }
    int excl = s[t] - tsum;
    if (t == 255) bsum[blockIdx.x] = s[255];
    if (idx     < n) data[idx]     = excl;
    if (idx + 1 < n) data[idx + 1] = excl + v.x;
    if (idx + 2 < n) data[idx + 2] = excl + v.x + v.y;
    if (idx + 3 < n) data[idx + 3] = excl + v.x + v.y + v.z;
}

// single block: exclusive scan of block sums (nb <= 256)
__global__ __launch_bounds__(256) void scan_sums(int* __restrict__ bsum, int nb)
{
    __shared__ int s[256];
    int t = threadIdx.x;
    int v = (t < nb) ? bsum[t] : 0;
    s[t] = v;
    __syncthreads();
    for (int off = 1; off < 256; off <<= 1) {
        int x = (t >= off) ? s[t - off] : 0;
        __syncthreads();
        s[t] += x;
        __syncthreads();
    }
    if (t < nb) bsum[t] = s[t] - v;
}

__global__ __launch_bounds__(256) void scan_add(
    int* __restrict__ data, int n, const int* __restrict__ bsum)
{
    int i = blockIdx.x * 256 + threadIdx.x;
    if (i < n) data[i] += bsum[i >> 10];
}

__global__ __launch_bounds__(256) void scatter_kernel(
    const int* __restrict__ ei, int E, int Etot,
    int* __restrict__ offs, int* __restrict__ esrc)
{
    int e = blockIdx.x * 256 + threadIdx.x;
    if (e >= Etot) return;
    int src, dst;
    if (e < E) { src = ei[e]; dst = ei[E + e]; }
    else       { src = dst = e - E; }
    int pos = atomicAdd(&offs[dst], 1);
    esrc[pos] = src;
}

// ---------------------------------------------------------------------------
// Layer-1 aggregation: one wave per dst node, F=128, 4 heads (C=32).
// Lane l handles features l and l+64 (heads l>>5 and 2+(l>>5)).
// Fuses softmax normalization + bias + ELU; writes X2 directly.
// ---------------------------------------------------------------------------
__global__ __launch_bounds__(256) void agg1(
    const int* __restrict__ offs, const int* __restrict__ esrc,
    const float* __restrict__ H, const float* __restrict__ As,
    const float* __restrict__ Ad, const float* __restrict__ bias,
    float* __restrict__ X2, int n)
{
    int v    = (blockIdx.x * 256 + threadIdx.x) >> 6;
    int lane = threadIdx.x & 63;
    if (v >= n) return;
    int end = offs[v];
    int beg = v ? offs[v - 1] : 0;
    int h1 = lane >> 5, h2 = 2 + (lane >> 5);
    float adv1 = Ad[(size_t)v * 4 + h1], adv2 = Ad[(size_t)v * 4 + h2];
    float acc0 = 0.f, acc1 = 0.f, den1 = 0.f, den2 = 0.f;
    for (int j = beg; j < end; ++j) {
        int s = esrc[j];
        float e1 = As[(size_t)s * 4 + h1] + adv1;
        float e2 = As[(size_t)s * 4 + h2] + adv2;
        e1 = e1 > 0.f ? e1 : NEG_SLOPE * e1;
        e2 = e2 > 0.f ? e2 : NEG_SLOPE * e2;
        float w1 = __expf(e1), w2 = __expf(e2);
        acc0 += w1 * H[(size_t)s * 128 + lane];
        acc1 += w2 * H[(size_t)s * 128 + 64 + lane];
        den1 += w1; den2 += w2;
    }
    float o0 = acc0 / (den1 + 1e-16f) + bias[lane];
    float o1 = acc1 / (den2 + 1e-16f) + bias[64 + lane];
    o0 = o0 > 0.f ? o0 : __expf(o0) - 1.f;     // ELU
    o1 = o1 > 0.f ? o1 : __expf(o1) - 1.f;
    X2[(size_t)v * 128 + lane]      = o0;
    X2[(size_t)v * 128 + 64 + lane] = o1;
}

// ---------------------------------------------------------------------------
// Layer-2 aggregation: one wave per dst node, F=64, 1 head. Writes d_out.
// ---------------------------------------------------------------------------
__global__ __launch_bounds__(256) void agg2(
    const int* __restrict__ offs, const int* __restrict__ esrc,
    const float* __restrict__ H, const float* __restrict__ As,
    const float* __restrict__ Ad, const float* __restrict__ bias,
    float* __restrict__ out, int n)
{
    int v    = (blockIdx.x * 256 + threadIdx.x) >> 6;
    int lane = threadIdx.x & 63;
    if (v >= n) return;
    int end = offs[v];
    int beg = v ? offs[v - 1] : 0;
    float adv = Ad[v];
    float acc = 0.f, den = 0.f;
    for (int j = beg; j < end; ++j) {
        int s = esrc[j];
        float e = As[s] + adv;
        e = e > 0.f ? e : NEG_SLOPE * e;
        float w = __expf(e);
        acc += w * H[(size_t)s * 64 + lane];
        den += w;
    }
    out[(size_t)v * 64 + lane] = acc / (den + 1e-16f) + bias[lane];
}

extern "C" void kernel_launch(void* const* d_in, const int* in_sizes, int n_in,
                              void* d_out, int out_size, void* d_ws, size_t ws_size,
                              hipStream_t stream)
{
    (void)n_in; (void)out_size; (void)ws_size;
    const float* x   = (const float*)d_in[0];
    const int*   ei  = (const int*)  d_in[1];
    const float* W1  = (const float*)d_in[2];
    const float* as1 = (const float*)d_in[3];
    const float* ad1 = (const float*)d_in[4];
    const float* b1  = (const float*)d_in[5];
    const float* W2  = (const float*)d_in[6];
    const float* as2 = (const float*)d_in[7];
    const float* ad2 = (const float*)d_in[8];
    const float* b2  = (const float*)d_in[9];
    float* out = (float*)d_out;

    const int n    = in_sizes[0] / 128;   // 100000
    const int E    = in_sizes[1] / 2;     // 1600000
    const int Etot = E + n;               // + self loops

    // Workspace layout. H2 overlays H1 (dead after L1 agg). As2/Ad2 overlay As1/Ad1.
    float* ws  = (float*)d_ws;
    float* H1  = ws;                            // n*128 (later: H2 = n*64)
    float* X2  = H1 + (size_t)n * 128;          // n*128
    float* As1 = X2 + (size_t)n * 128;          // n*4   (later: As2 = n)
    float* Ad1 = As1 + (size_t)n * 4;           // n*4   (later: Ad2 = n)
    int* offs  = (int*)(Ad1 + (size_t)n * 4);   // n (deg -> excl-scan -> ends)
    int* bsum  = offs + n;                      // 128
    int* esrc  = bsum + 128;                    // Etot

    const int nb = (n + 1023) / 1024;           // scan blocks (98)

    // ---- CSR build (shared by both layers) ----
    hipMemsetAsync(offs, 0, sizeof(int) * (size_t)n, stream);
    hist_kernel<<<(Etot + 255) / 256, 256, 0, stream>>>(ei, E, Etot, offs);
    scan_blocks<<<nb, 256, 0, stream>>>(offs, n, bsum);
    scan_sums<<<1, 256, 0, stream>>>(bsum, nb);
    scan_add<<<(n + 255) / 256, 256, 0, stream>>>(offs, n, bsum);
    scatter_kernel<<<(Etot + 255) / 256, 256, 0, stream>>>(ei, E, Etot, offs, esrc);

    // ---- Layer 1 ----
    gemm_att<128, 32, 32><<<(n + 31) / 32, 256, 0, stream>>>(x, W1, as1, ad1, H1, As1, Ad1, n);
    agg1<<<(n * 64 + 255) / 256, 256, 0, stream>>>(offs, esrc, H1, As1, Ad1, b1, X2, n);

    // ---- Layer 2 ----
    gemm_att<64, 64, 64><<<(n + 63) / 64, 256, 0, stream>>>(X2, W2, as2, ad2, H1, As1, Ad1, n);
    agg2<<<(n * 64 + 255) / 256, 256, 0, stream>>>(offs, esrc, H1, As1, Ad1, b2, out, n);
}

// Round 3
// 560.611 us; speedup vs baseline: 2.8646x; 1.3645x over previous
//
#include <hip/hip_runtime.h>
#include <hip/hip_fp16.h>

#define NEG_SLOPE 0.2f

// ---------------------------------------------------------------------------
// Fused GEMM + attention-logit kernel.
//   H[n, BN]   = fp16( X[n, 128] @ W[128, BN] )     (message payload, fp16)
//   As[n, hd]  = sum_c Hf32[n, hd*C+c] * atts[...]  (logits from fp32 accs)
//   Ad[n, hd]  = sum_c Hf32[n, hd*C+c] * attd[...]
// ---------------------------------------------------------------------------
template<int BN, int BM, int C>
__global__ __launch_bounds__(256) void gemm_att(
    const float* __restrict__ X, const float* __restrict__ W,
    const float* __restrict__ atts, const float* __restrict__ attd,
    __half* __restrict__ H, float* __restrict__ As, float* __restrict__ Ad,
    int n)
{
    constexpr int K  = 128;
    constexpr int CG = BN / 4;          // column groups of 4
    constexpr int RW = C / 4;           // shuffle-reduce width (lanes per head)
    constexpr int HEADS = BN / C;

    __shared__ float Wl[K * BN];
    __shared__ float Xl[K * BM];

    const int t = threadIdx.x;
    for (int i = t; i < K * BN / 4; i += 256)
        ((float4*)Wl)[i] = ((const float4*)W)[i];

    const int cg   = t % CG;
    const int rg   = t / CG;
    const int col0 = cg * 4;
    const int head = col0 / C;
    const float s0 = atts[col0], s1 = atts[col0+1], s2 = atts[col0+2], s3 = atts[col0+3];
    const float d0 = attd[col0], d1 = attd[col0+1], d2 = attd[col0+2], d3 = attd[col0+3];

    const int numTiles = (n + BM - 1) / BM;
    for (int tile = blockIdx.x; tile < numTiles; tile += gridDim.x) {
        const int row0 = tile * BM;
        __syncthreads();
        for (int i = t; i < BM * (K / 4); i += 256) {
            int r = i % BM, k4 = i / BM;
            int row = row0 + r;
            float4 v = make_float4(0.f, 0.f, 0.f, 0.f);
            if (row < n) v = ((const float4*)(X + (size_t)row * K))[k4];
            Xl[(k4*4+0)*BM + r] = v.x;
            Xl[(k4*4+1)*BM + r] = v.y;
            Xl[(k4*4+2)*BM + r] = v.z;
            Xl[(k4*4+3)*BM + r] = v.w;
        }
        __syncthreads();

        float acc[4][4];
        #pragma unroll
        for (int a = 0; a < 4; ++a)
            #pragma unroll
            for (int b = 0; b < 4; ++b) acc[a][b] = 0.f;

        #pragma unroll 8
        for (int k = 0; k < K; ++k) {
            float4 a = ((const float4*)(Xl + k * BM))[rg];
            float4 b = ((const float4*)(Wl + k * BN))[cg];
            acc[0][0] += a.x*b.x; acc[0][1] += a.x*b.y; acc[0][2] += a.x*b.z; acc[0][3] += a.x*b.w;
            acc[1][0] += a.y*b.x; acc[1][1] += a.y*b.y; acc[1][2] += a.y*b.z; acc[1][3] += a.y*b.w;
            acc[2][0] += a.z*b.x; acc[2][1] += a.z*b.y; acc[2][2] += a.z*b.z; acc[2][3] += a.z*b.w;
            acc[3][0] += a.w*b.x; acc[3][1] += a.w*b.y; acc[3][2] += a.w*b.z; acc[3][3] += a.w*b.w;
        }

        #pragma unroll
        for (int ri = 0; ri < 4; ++ri) {
            int row = row0 + rg * 4 + ri;
            bool ok = row < n;
            if (ok) {
                __half2 p0 = __floats2half2_rn(acc[ri][0], acc[ri][1]);
                __half2 p1 = __floats2half2_rn(acc[ri][2], acc[ri][3]);
                uint2 u;
                u.x = *(unsigned*)&p0;
                u.y = *(unsigned*)&p1;
                ((uint2*)(H + (size_t)row * BN))[cg] = u;   // 8B packed store
            }
            float ps = acc[ri][0]*s0 + acc[ri][1]*s1 + acc[ri][2]*s2 + acc[ri][3]*s3;
            float pd = acc[ri][0]*d0 + acc[ri][1]*d1 + acc[ri][2]*d2 + acc[ri][3]*d3;
            #pragma unroll
            for (int off = RW / 2; off > 0; off >>= 1) {
                ps += __shfl_down(ps, off, RW);
                pd += __shfl_down(pd, off, RW);
            }
            if (ok && (cg % RW) == 0) {
                As[(size_t)row * HEADS + head] = ps;
                Ad[(size_t)row * HEADS + head] = pd;
            }
        }
    }
}

// ---------------------------------------------------------------------------
// CSR build: histogram of dst, block-wise exclusive scan, scatter src ids.
// After scatter, offs[v] == end(v); beg(v) = (v==0 ? 0 : offs[v-1]).
// ---------------------------------------------------------------------------
__global__ __launch_bounds__(256) void hist_kernel(
    const int* __restrict__ ei, int E, int Etot, int* __restrict__ deg)
{
    int e = blockIdx.x * 256 + threadIdx.x;
    if (e >= Etot) return;
    int dst = (e < E) ? ei[E + e] : (e - E);
    atomicAdd(&deg[dst], 1);
}

__global__ __launch_bounds__(256) void scan_blocks(
    int* __restrict__ data, int n, int* __restrict__ bsum)
{
    __shared__ int s[256];
    int t = threadIdx.x;
    int idx = blockIdx.x * 1024 + t * 4;
    int4 v = make_int4(0, 0, 0, 0);
    if (idx + 3 < n)      v = *(const int4*)(data + idx);
    else {
        if (idx     < n) v.x = data[idx];
        if (idx + 1 < n) v.y = data[idx+1];
        if (idx + 2 < n) v.z = data[idx+2];
        if (idx + 3 < n) v.w = data[idx+3];
    }
    int tsum = v.x + v.y + v.z + v.w;
    s[t] = tsum;
    __syncthreads();
    for (int off = 1; off < 256; off <<= 1) {
        int x = (t >= off) ? s[t - off] : 0;
        __syncthreads();
        s[t] += x;
        __syncthreads();
    }
    int excl = s[t] - tsum;
    if (t == 255) bsum[blockIdx.x] = s[255];
    if (idx     < n) data[idx]     = excl;
    if (idx + 1 < n) data[idx + 1] = excl + v.x;
    if (idx + 2 < n) data[idx + 2] = excl + v.x + v.y;
    if (idx + 3 < n) data[idx + 3] = excl + v.x + v.y + v.z;
}

__global__ __launch_bounds__(256) void scan_sums(int* __restrict__ bsum, int nb)
{
    __shared__ int s[256];
    int t = threadIdx.x;
    int v = (t < nb) ? bsum[t] : 0;
    s[t] = v;
    __syncthreads();
    for (int off = 1; off < 256; off <<= 1) {
        int x = (t >= off) ? s[t - off] : 0;
        __syncthreads();
        s[t] += x;
        __syncthreads();
    }
    if (t < nb) bsum[t] = s[t] - v;
}

__global__ __launch_bounds__(256) void scan_add(
    int* __restrict__ data, int n, const int* __restrict__ bsum)
{
    int i = blockIdx.x * 256 + threadIdx.x;
    if (i < n) data[i] += bsum[i >> 10];
}

__global__ __launch_bounds__(256) void scatter_kernel(
    const int* __restrict__ ei, int E, int Etot,
    int* __restrict__ offs, int* __restrict__ esrc)
{
    int e = blockIdx.x * 256 + threadIdx.x;
    if (e >= Etot) return;
    int src, dst;
    if (e < E) { src = ei[e]; dst = ei[E + e]; }
    else       { src = dst = e - E; }
    int pos = atomicAdd(&offs[dst], 1);
    esrc[pos] = src;
}

// ---------------------------------------------------------------------------
// Layer-1 aggregation: one wave per dst node, F=128 (fp16), 4 heads (C=32).
// Lane l handles feature pair (2l, 2l+1) -> head l>>4. Edge loop unrolled x4.
// Fuses softmax normalization + bias + ELU; writes fp32 X2 directly.
// ---------------------------------------------------------------------------
__global__ __launch_bounds__(256) void agg1(
    const int* __restrict__ offs, const int* __restrict__ esrc,
    const __half2* __restrict__ Hh, const float* __restrict__ As,
    const float* __restrict__ Ad, const float* __restrict__ bias,
    float* __restrict__ X2, int n)
{
    int v    = (blockIdx.x * 256 + threadIdx.x) >> 6;
    int lane = threadIdx.x & 63;
    if (v >= n) return;
    int end = offs[v];
    int beg = v ? offs[v - 1] : 0;
    int head = lane >> 4;
    float adv = Ad[(size_t)v * 4 + head];
    float accx = 0.f, accy = 0.f, den = 0.f;
    int j = beg;
    for (; j + 3 < end; j += 4) {
        int s0 = esrc[j], s1 = esrc[j+1], s2 = esrc[j+2], s3 = esrc[j+3];
        float e0 = As[(size_t)s0*4 + head] + adv;
        float e1 = As[(size_t)s1*4 + head] + adv;
        float e2 = As[(size_t)s2*4 + head] + adv;
        float e3 = As[(size_t)s3*4 + head] + adv;
        __half2 q0 = Hh[(size_t)s0*64 + lane];
        __half2 q1 = Hh[(size_t)s1*64 + lane];
        __half2 q2 = Hh[(size_t)s2*64 + lane];
        __half2 q3 = Hh[(size_t)s3*64 + lane];
        e0 = e0 > 0.f ? e0 : NEG_SLOPE*e0;  float w0 = __expf(e0);
        e1 = e1 > 0.f ? e1 : NEG_SLOPE*e1;  float w1 = __expf(e1);
        e2 = e2 > 0.f ? e2 : NEG_SLOPE*e2;  float w2 = __expf(e2);
        e3 = e3 > 0.f ? e3 : NEG_SLOPE*e3;  float w3 = __expf(e3);
        float2 f0 = __half22float2(q0);
        float2 f1 = __half22float2(q1);
        float2 f2 = __half22float2(q2);
        float2 f3 = __half22float2(q3);
        accx += w0*f0.x + w1*f1.x + w2*f2.x + w3*f3.x;
        accy += w0*f0.y + w1*f1.y + w2*f2.y + w3*f3.y;
        den  += w0 + w1 + w2 + w3;
    }
    for (; j < end; ++j) {
        int s = esrc[j];
        float e = As[(size_t)s*4 + head] + adv;
        e = e > 0.f ? e : NEG_SLOPE*e;
        float w = __expf(e);
        float2 f = __half22float2(Hh[(size_t)s*64 + lane]);
        accx += w*f.x; accy += w*f.y; den += w;
    }
    float inv = 1.f / (den + 1e-16f);
    float2 b = ((const float2*)bias)[lane];
    float ox = accx*inv + b.x, oy = accy*inv + b.y;
    ox = ox > 0.f ? ox : __expf(ox) - 1.f;     // ELU
    oy = oy > 0.f ? oy : __expf(oy) - 1.f;
    ((float2*)(X2 + (size_t)v * 128))[lane] = make_float2(ox, oy);
}

// ---------------------------------------------------------------------------
// Layer-2 aggregation: one wave per dst node, F=64 (fp16), 1 head.
// Half-wave 0 takes even edges, half-wave 1 odd edges (32 lanes cover the
// 32 half2 feature pairs); shuffle-combine at the end. Writes d_out (fp32).
// ---------------------------------------------------------------------------
__global__ __launch_bounds__(256) void agg2(
    const int* __restrict__ offs, const int* __restrict__ esrc,
    const __half2* __restrict__ Hh, const float* __restrict__ As,
    const float* __restrict__ Ad, const float* __restrict__ bias,
    float* __restrict__ out, int n)
{
    int v    = (blockIdx.x * 256 + threadIdx.x) >> 6;
    int lane = threadIdx.x & 63;
    if (v >= n) return;
    int half = lane >> 5;
    int li   = lane & 31;
    int end = offs[v];
    int beg = v ? offs[v - 1] : 0;
    float adv = Ad[v];
    float accx = 0.f, accy = 0.f, den = 0.f;
    int j = beg + half;
    for (; j + 2 < end; j += 4) {          // this half's edges, unrolled x2
        int s0 = esrc[j], s1 = esrc[j+2];
        float e0 = As[s0] + adv;
        float e1 = As[s1] + adv;
        __half2 q0 = Hh[(size_t)s0*32 + li];
        __half2 q1 = Hh[(size_t)s1*32 + li];
        e0 = e0 > 0.f ? e0 : NEG_SLOPE*e0;  float w0 = __expf(e0);
        e1 = e1 > 0.f ? e1 : NEG_SLOPE*e1;  float w1 = __expf(e1);
        float2 f0 = __half22float2(q0);
        float2 f1 = __half22float2(q1);
        accx += w0*f0.x + w1*f1.x;
        accy += w0*f0.y + w1*f1.y;
        den  += w0 + w1;
    }
    for (; j < end; j += 2) {
        int s = esrc[j];
        float e = As[s] + adv;
        e = e > 0.f ? e : NEG_SLOPE*e;
        float w = __expf(e);
        float2 f = __half22float2(Hh[(size_t)s*32 + li]);
        accx += w*f.x; accy += w*f.y; den += w;
    }
    accx += __shfl_xor(accx, 32);
    accy += __shfl_xor(accy, 32);
    den  += __shfl_xor(den, 32);
    if (half == 0) {
        float inv = 1.f / (den + 1e-16f);
        float2 b = ((const float2*)bias)[li];
        ((float2*)(out + (size_t)v * 64))[li] =
            make_float2(accx*inv + b.x, accy*inv + b.y);
    }
}

extern "C" void kernel_launch(void* const* d_in, const int* in_sizes, int n_in,
                              void* d_out, int out_size, void* d_ws, size_t ws_size,
                              hipStream_t stream)
{
    (void)n_in; (void)out_size; (void)ws_size;
    const float* x   = (const float*)d_in[0];
    const int*   ei  = (const int*)  d_in[1];
    const float* W1  = (const float*)d_in[2];
    const float* as1 = (const float*)d_in[3];
    const float* ad1 = (const float*)d_in[4];
    const float* b1  = (const float*)d_in[5];
    const float* W2  = (const float*)d_in[6];
    const float* as2 = (const float*)d_in[7];
    const float* ad2 = (const float*)d_in[8];
    const float* b2  = (const float*)d_in[9];
    float* out = (float*)d_out;

    const int n    = in_sizes[0] / 128;   // 100000
    const int E    = in_sizes[1] / 2;     // 1600000
    const int Etot = E + n;               // + self loops

    // Workspace layout (bytes). Layer-2 buffers overlay consumed layer-1 ones.
    char* p = (char*)d_ws;
    __half* Hh = (__half*)p;  p += (size_t)n * 128 * sizeof(__half);  // 25.6MB (L2: n*64)
    float* X2  = (float*)p;   p += (size_t)n * 128 * sizeof(float);   // 51.2MB
    float* As1 = (float*)p;   p += (size_t)n * 4 * sizeof(float);     // (L2: n)
    float* Ad1 = (float*)p;   p += (size_t)n * 4 * sizeof(float);     // (L2: n)
    int* offs  = (int*)p;     p += (size_t)n * sizeof(int);
    int* bsum  = (int*)p;     p += 128 * sizeof(int);
    int* esrc  = (int*)p;                                              // Etot ints

    const int nb = (n + 1023) / 1024;

    // ---- CSR build (shared by both layers) ----
    hipMemsetAsync(offs, 0, sizeof(int) * (size_t)n, stream);
    hist_kernel<<<(Etot + 255) / 256, 256, 0, stream>>>(ei, E, Etot, offs);
    scan_blocks<<<nb, 256, 0, stream>>>(offs, n, bsum);
    scan_sums<<<1, 256, 0, stream>>>(bsum, nb);
    scan_add<<<(n + 255) / 256, 256, 0, stream>>>(offs, n, bsum);
    scatter_kernel<<<(Etot + 255) / 256, 256, 0, stream>>>(ei, E, Etot, offs, esrc);

    // ---- Layer 1 ----
    gemm_att<128, 32, 32><<<(n + 31) / 32, 256, 0, stream>>>(x, W1, as1, ad1, Hh, As1, Ad1, n);
    agg1<<<(n * 64 + 255) / 256, 256, 0, stream>>>(offs, esrc, (const __half2*)Hh, As1, Ad1, b1, X2, n);

    // ---- Layer 2 ----
    gemm_att<64, 64, 64><<<(n + 63) / 64, 256, 0, stream>>>(X2, W2, as2, ad2, Hh, As1, Ad1, n);
    agg2<<<(n * 64 + 255) / 256, 256, 0, stream>>>(offs, esrc, (const __half2*)Hh, As1, Ad1, b2, out, n);
}